// Round 1
// baseline (362.983 us; speedup 1.0000x reference)
//
#include <hip/hip_runtime.h>
#include <stdint.h>

#define B_ 4
#define T1_ 4096
#define T2_ 2048
#define C_ 512
#define H_ 8
#define D_ 64
#define M1_ (B_*T1_)   // 16384
#define M2_ (B_*T2_)   // 8192

using f32x4 = __attribute__((ext_vector_type(4))) float;
using bf16x8 = __attribute__((ext_vector_type(8))) __bf16;
using us8 = __attribute__((ext_vector_type(8))) unsigned short;
using us4 = __attribute__((ext_vector_type(4))) unsigned short;

__device__ __forceinline__ unsigned short f2bf(float f){
  unsigned int u = __builtin_bit_cast(unsigned int, f);
  unsigned int r = (u + 0x7fffu + ((u >> 16) & 1u)) >> 16;
  return (unsigned short)r;
}
__device__ __forceinline__ float bf2f(unsigned short u){
  return __builtin_bit_cast(float, ((unsigned int)u) << 16);
}

__device__ __forceinline__ f32x4 mfma16(us8 a, us8 b, f32x4 c){
  return __builtin_amdgcn_mfma_f32_16x16x32_bf16(
      __builtin_bit_cast(bf16x8, a), __builtin_bit_cast(bf16x8, b), c, 0, 0, 0);
}

typedef const __attribute__((address_space(1))) unsigned int gu32;
typedef __attribute__((address_space(3))) unsigned int lu32;
__device__ __forceinline__ void gl_lds16(const void* g, void* l){
  __builtin_amdgcn_global_load_lds((gu32*)g, (lu32*)l, 16, 0, 0);
}

// ---------------- fp32 -> bf16 convert ----------------
__global__ __launch_bounds__(256) void cvt_bf16(const float* __restrict__ in,
                                                unsigned short* __restrict__ out, int n4){
  int i = blockIdx.x * 256 + threadIdx.x;
  if (i >= n4) return;
  f32x4 v = ((const f32x4*)in)[i];
  us4 o;
  #pragma unroll
  for (int j = 0; j < 4; ++j) o[j] = f2bf(v[j]);
  ((us4*)out)[i] = o;
}

// ---------------- GEMM: C = A[M,K] @ Bw[N,K]^T + bias ----------------
// MODE 0: fp32 out; MODE 1: bf16 out
template<int MODE>
__global__ __launch_bounds__(256) void gemm_bt(const unsigned short* __restrict__ A,
                                               const unsigned short* __restrict__ Bw,
                                               const float* __restrict__ bias,
                                               void* __restrict__ out, int M, int N, int Kd){
  __shared__ unsigned short ldsA[128*32];
  __shared__ unsigned short ldsB[128*32];
  const int m0 = blockIdx.x * 128, n0 = blockIdx.y * 128;
  const int t = threadIdx.x;
  const int w = t >> 6, l = t & 63;
  const int wr = w >> 1, wc = w & 1;
  const int lr = l & 15, lk = l >> 4;
  f32x4 acc[4][4] = {};
  for (int k0 = 0; k0 < Kd; k0 += 32){
    {
      int c = t, row = c >> 2, off = (c & 3) * 8;
      gl_lds16(A  + (size_t)(m0+row)*Kd + k0 + off, &ldsA[c*8]);
      gl_lds16(Bw + (size_t)(n0+row)*Kd + k0 + off, &ldsB[c*8]);
      c = t + 256; row = c >> 2; off = (c & 3) * 8;
      gl_lds16(A  + (size_t)(m0+row)*Kd + k0 + off, &ldsA[c*8]);
      gl_lds16(Bw + (size_t)(n0+row)*Kd + k0 + off, &ldsB[c*8]);
    }
    __syncthreads();
    us8 af[4], bfr[4];
    #pragma unroll
    for (int mt = 0; mt < 4; ++mt)
      af[mt] = *(const us8*)&ldsA[(wr*64 + mt*16 + lr)*32 + lk*8];
    #pragma unroll
    for (int nt = 0; nt < 4; ++nt)
      bfr[nt] = *(const us8*)&ldsB[(wc*64 + nt*16 + lr)*32 + lk*8];
    #pragma unroll
    for (int mt = 0; mt < 4; ++mt)
      #pragma unroll
      for (int nt = 0; nt < 4; ++nt)
        acc[mt][nt] = mfma16(af[mt], bfr[nt], acc[mt][nt]);
    __syncthreads();
  }
  #pragma unroll
  for (int mt = 0; mt < 4; ++mt)
    #pragma unroll
    for (int nt = 0; nt < 4; ++nt)
      #pragma unroll
      for (int r = 0; r < 4; ++r){
        int row = m0 + wr*64 + mt*16 + lk*4 + r;
        int col = n0 + wc*64 + nt*16 + lr;
        float v = acc[mt][nt][r] + bias[col];
        if constexpr (MODE == 0) ((float*)out)[(size_t)row*N + col] = v;
        else ((unsigned short*)out)[(size_t)row*N + col] = f2bf(v);
      }
}

// ---------------- per-64-group softmax: fp32 logits -> bf16 ----------------
__global__ __launch_bounds__(256) void softmax64(const float* __restrict__ in,
                                                 unsigned short* __restrict__ out, int rows){
  int w = threadIdx.x >> 6, l = threadIdx.x & 63;
  int r = blockIdx.x * 4 + w;
  if (r >= rows) return;
  const float* ip = in + (size_t)r * C_;
  unsigned short* op = out + (size_t)r * C_;
  #pragma unroll 1
  for (int g = 0; g < 8; ++g){
    float x = ip[g*64 + l];
    float m = x;
    #pragma unroll
    for (int s = 32; s; s >>= 1) m = fmaxf(m, __shfl_xor(m, s, 64));
    float e = expf(x - m);
    float ss = e;
    #pragma unroll
    for (int s = 32; s; s >>= 1) ss += __shfl_xor(ss, s, 64);
    op[g*64 + l] = f2bf(e / ss);
  }
}

// ---------------- column sums of k (per b): ksum_i[b][c] += sum ----------------
__global__ __launch_bounds__(512) void colsum(const unsigned short* __restrict__ kb,
                                              float* __restrict__ ksum_i){
  int b = blockIdx.x, ch = blockIdx.y, c = threadIdx.x;
  const unsigned short* p = kb + ((size_t)(b*T2_ + ch*256))*C_ + c;
  float s = 0.f;
  for (int r2 = 0; r2 < 256; ++r2) s += bf2f(p[(size_t)r2 * C_]);
  atomicAdd(&ksum_i[b*C_ + c], s);
}

// ---------------- context partials: part[ch][bh][e][d] = sum_n k[n,d] v[n,e] ----------------
__global__ __launch_bounds__(256) void ctx_partial(const unsigned short* __restrict__ kb,
                                                   const unsigned short* __restrict__ vb,
                                                   float* __restrict__ part){
  __shared__ unsigned short lk_[256*64];
  __shared__ unsigned short lv_[256*64];
  int bh = blockIdx.x, ch = blockIdx.y;
  int b = bh >> 3, h = bh & 7;
  int t = threadIdx.x;
  size_t rowbase = (size_t)(b*T2_ + ch*256);
  #pragma unroll
  for (int it = 0; it < 8; ++it){
    int c = t + it*256;           // 0..2047
    int row = c >> 3, off = (c & 7) * 8;
    gl_lds16(kb + (rowbase + row)*C_ + h*D_ + off, &lk_[c*8]);
    gl_lds16(vb + (rowbase + row)*C_ + h*D_ + off, &lv_[c*8]);
  }
  __syncthreads();
  int d0 = (t & 15) * 4, e0 = (t >> 4) * 4;
  float acc[4][4] = {};
  for (int n = 0; n < 256; ++n){
    us4 kq = *(const us4*)&lk_[n*64 + d0];
    us4 vq = *(const us4*)&lv_[n*64 + e0];
    float kf[4], vf[4];
    #pragma unroll
    for (int j = 0; j < 4; ++j){ kf[j] = bf2f(kq[j]); vf[j] = bf2f(vq[j]); }
    #pragma unroll
    for (int jd = 0; jd < 4; ++jd)
      #pragma unroll
      for (int je = 0; je < 4; ++je)
        acc[jd][je] += kf[jd] * vf[je];
  }
  float* dst = part + ((size_t)(ch*32 + bh)) * 4096;
  #pragma unroll
  for (int jd = 0; jd < 4; ++jd)
    #pragma unroll
    for (int je = 0; je < 4; ++je)
      dst[(e0+je)*64 + (d0+jd)] = acc[jd][je];
}

__global__ __launch_bounds__(256) void ctx_reduce(const float* __restrict__ part,
                                                  float* __restrict__ ctxTi){
  int bh = blockIdx.x, t = threadIdx.x;
  for (int idx = t; idx < 4096; idx += 256){
    float s = 0.f;
    #pragma unroll
    for (int ch = 0; ch < 8; ++ch) s += part[((size_t)(ch*32 + bh))*4096 + idx];
    ctxTi[(size_t)bh*4096 + idx] = s;
  }
}

// ---------------- combine: omid = q + sum_i (q @ ctx_i) * Dinv_i ----------------
__global__ __launch_bounds__(256) void combine(const unsigned short* __restrict__ qb,
                                               const float* __restrict__ ctxT,
                                               const float* __restrict__ ksum,
                                               unsigned short* __restrict__ omid){
  int tc = blockIdx.x, bh = blockIdx.y;
  int b = bh >> 3, h = bh & 7;
  int w = threadIdx.x >> 6, l = threadIdx.x & 63;
  int rbase = tc*256 + w*64;
  int lr = l & 15, lk = l >> 4;

  // A fragments: q rows
  us8 afr[4][2];
  #pragma unroll
  for (int mt = 0; mt < 4; ++mt)
    #pragma unroll
    for (int kk = 0; kk < 2; ++kk){
      int row = rbase + mt*16 + lr;
      afr[mt][kk] = *(const us8*)(qb + ((size_t)(b*T1_ + row))*C_ + h*D_ + kk*32 + lk*8);
    }

  // denominator: B columns = ksum_i  (cols 0..2), rest zero
  us8 bden[2];
  #pragma unroll
  for (int kk = 0; kk < 2; ++kk){
    us8 tmp = {};
    if (lr < 3){
      const float* kp = ksum + ((size_t)lr*B_ + b)*C_ + h*D_ + kk*32 + lk*8;
      f32x4 c0 = *(const f32x4*)kp;
      f32x4 c1 = *(const f32x4*)(kp + 4);
      #pragma unroll
      for (int j = 0; j < 4; ++j){ tmp[j] = f2bf(c0[j]); tmp[4+j] = f2bf(c1[j]); }
    }
    bden[kk] = tmp;
  }
  f32x4 den[4] = {};
  #pragma unroll
  for (int mt = 0; mt < 4; ++mt)
    #pragma unroll
    for (int kk = 0; kk < 2; ++kk)
      den[mt] = mfma16(afr[mt][kk], bden[kk], den[mt]);

  f32x4 dinv[3][4];
  #pragma unroll
  for (int i = 0; i < 3; ++i)
    #pragma unroll
    for (int mt = 0; mt < 4; ++mt)
      #pragma unroll
      for (int r = 0; r < 4; ++r){
        float dd = __shfl(den[mt][r], (l & 48) | i, 64);
        dinv[i][mt][r] = 1.0f / (dd + 1e-8f);
      }

  #pragma unroll 1
  for (int nt = 0; nt < 4; ++nt){
    int col = h*D_ + nt*16 + lr;
    f32x4 oacc[4];
    #pragma unroll
    for (int mt = 0; mt < 4; ++mt)
      #pragma unroll
      for (int r = 0; r < 4; ++r){
        int row = rbase + mt*16 + lk*4 + r;
        oacc[mt][r] = bf2f(qb[((size_t)(b*T1_ + row))*C_ + col]);
      }
    #pragma unroll 1
    for (int i = 0; i < 3; ++i){
      us8 bfr[2];
      #pragma unroll
      for (int kk = 0; kk < 2; ++kk){
        const float* cp = ctxT + ((size_t)(i*32 + bh))*4096 + (nt*16 + lr)*64 + kk*32 + lk*8;
        f32x4 c0 = *(const f32x4*)cp;
        f32x4 c1 = *(const f32x4*)(cp + 4);
        us8 tmp;
        #pragma unroll
        for (int j = 0; j < 4; ++j){ tmp[j] = f2bf(c0[j]); tmp[4+j] = f2bf(c1[j]); }
        bfr[kk] = tmp;
      }
      f32x4 pacc[4] = {};
      #pragma unroll
      for (int mt = 0; mt < 4; ++mt)
        #pragma unroll
        for (int kk = 0; kk < 2; ++kk)
          pacc[mt] = mfma16(afr[mt][kk], bfr[kk], pacc[mt]);
      #pragma unroll
      for (int mt = 0; mt < 4; ++mt)
        #pragma unroll
        for (int r = 0; r < 4; ++r)
          oacc[mt][r] += pacc[mt][r] * dinv[i][mt][r];
    }
    #pragma unroll
    for (int mt = 0; mt < 4; ++mt)
      #pragma unroll
      for (int r = 0; r < 4; ++r){
        int row = rbase + mt*16 + lk*4 + r;
        omid[((size_t)(b*T1_ + row))*C_ + col] = f2bf(oacc[mt][r]);
      }
  }
}

extern "C" void kernel_launch(void* const* d_in, const int* in_sizes, int n_in,
                              void* d_out, int out_size, void* d_ws, size_t ws_size,
                              hipStream_t stream){
  const float* x  = (const float*)d_in[0];
  const float* y[3] = {(const float*)d_in[1], (const float*)d_in[2], (const float*)d_in[3]};
  const float* Wq = (const float*)d_in[4];
  const float* bq = (const float*)d_in[5];
  const float* Wk = (const float*)d_in[6];
  const float* bk = (const float*)d_in[7];
  const float* Wv = (const float*)d_in[8];
  const float* bv = (const float*)d_in[9];
  const float* Wo = (const float*)d_in[10];
  const float* bo = (const float*)d_in[11];

  char* ws = (char*)d_ws;
  size_t off = 0;
  auto alloc = [&](size_t bytes)->char*{
    char* p = ws + off; off += (bytes + 1023) & ~((size_t)1023); return p;
  };
  unsigned short* xb  = (unsigned short*)alloc((size_t)M1_*C_*2);
  unsigned short* yb  = (unsigned short*)alloc((size_t)M2_*C_*2);
  unsigned short* wqb = (unsigned short*)alloc((size_t)C_*C_*2);
  unsigned short* wkb = (unsigned short*)alloc((size_t)3*C_*C_*2);
  unsigned short* wvb = (unsigned short*)alloc((size_t)3*C_*C_*2);
  unsigned short* wob = (unsigned short*)alloc((size_t)C_*C_*2);
  float*          logits = (float*)alloc((size_t)M1_*C_*4);
  unsigned short* qb  = (unsigned short*)alloc((size_t)M1_*C_*2);
  unsigned short* kb  = (unsigned short*)alloc((size_t)M2_*C_*2);
  unsigned short* vb  = (unsigned short*)alloc((size_t)M2_*C_*2);
  float*          part = (float*)alloc((size_t)8*32*4096*4);
  float*          ctxT = (float*)alloc((size_t)3*32*4096*4);
  float*          ksum = (float*)alloc((size_t)3*B_*C_*4);
  unsigned short* omid = (unsigned short*)alloc((size_t)M1_*C_*2);

  hipMemsetAsync(ksum, 0, (size_t)3*B_*C_*4, stream);

  cvt_bf16<<<(M1_*C_/4 + 255)/256, 256, 0, stream>>>(x, xb, M1_*C_/4);
  cvt_bf16<<<(C_*C_/4 + 255)/256, 256, 0, stream>>>(Wq, wqb, C_*C_/4);
  cvt_bf16<<<(3*C_*C_/4 + 255)/256, 256, 0, stream>>>(Wk, wkb, 3*C_*C_/4);
  cvt_bf16<<<(3*C_*C_/4 + 255)/256, 256, 0, stream>>>(Wv, wvb, 3*C_*C_/4);
  cvt_bf16<<<(C_*C_/4 + 255)/256, 256, 0, stream>>>(Wo, wob, C_*C_/4);

  gemm_bt<0><<<dim3(M1_/128, C_/128), 256, 0, stream>>>(xb, wqb, bq, logits, M1_, C_, C_);
  softmax64<<<M1_/4, 256, 0, stream>>>(logits, qb, M1_);

  for (int i = 0; i < 3; ++i){
    cvt_bf16<<<(M2_*C_/4 + 255)/256, 256, 0, stream>>>(y[i], yb, M2_*C_/4);
    gemm_bt<0><<<dim3(M2_/128, C_/128), 256, 0, stream>>>(yb, wkb + (size_t)i*C_*C_, bk + i*C_, logits, M2_, C_, C_);
    softmax64<<<M2_/4, 256, 0, stream>>>(logits, kb, M2_);
    colsum<<<dim3(B_, 8), 512, 0, stream>>>(kb, ksum + (size_t)i*B_*C_);
    gemm_bt<1><<<dim3(M2_/128, C_/128), 256, 0, stream>>>(yb, wvb + (size_t)i*C_*C_, bv + i*C_, vb, M2_, C_, C_);
    ctx_partial<<<dim3(32, 8), 256, 0, stream>>>(kb, vb, part);
    ctx_reduce<<<32, 256, 0, stream>>>(part, ctxT + (size_t)i*32*4096);
  }

  combine<<<dim3(16, 32), 256, 0, stream>>>(qb, ctxT, ksum, omid);
  gemm_bt<0><<<dim3(M1_/128, C_/128), 256, 0, stream>>>(omid, wob, bo, d_out, M1_, C_, C_);
}